// Round 9
// baseline (407.868 us; speedup 1.0000x reference)
//
#include <hip/hip_runtime.h>
#include <math.h>

#define N_NODES 20000
#define N_EDGES 320000
#define DIM_IN 128
#define HID 64
#define HEADS 4
#define LAYERS 3
#define GRAPHS 128
#define HOP 68   // padded LDS row stride (floats): 68*4B=272B, 16B-aligned, 2-way bank alias only

typedef unsigned short ushort;
typedef ushort ushort8 __attribute__((ext_vector_type(8)));
typedef ushort ushort4v __attribute__((ext_vector_type(4)));
typedef short short8 __attribute__((ext_vector_type(8)));
typedef float f32x4 __attribute__((ext_vector_type(4)));

__device__ __forceinline__ float bf2f(ushort u) {
    return __uint_as_float(((unsigned int)u) << 16);
}
__device__ __forceinline__ ushort f2bf(float f) {
    unsigned int b = __float_as_uint(f);
    return (ushort)((b + 0x7FFFu + ((b >> 16) & 1u)) >> 16);
}

// ---------------- CSR build ----------------

__global__ void hist_kernel(const int* __restrict__ dst, int* __restrict__ counts, int n) {
    int e = blockIdx.x * 256 + threadIdx.x;
    if (e < n) atomicAdd(&counts[dst[e]], 1);
}

__global__ __launch_bounds__(256) void blocksum_kernel(const int* __restrict__ counts,
                                                       int* __restrict__ bsum, int n) {
    int i = blockIdx.x * 256 + threadIdx.x;
    int v = (i < n) ? counts[i] : 0;
    int lane = threadIdx.x & 63, wave = threadIdx.x >> 6;
#pragma unroll
    for (int off = 32; off >= 1; off >>= 1) v += __shfl_xor(v, off);
    __shared__ int ws[4];
    if (lane == 0) ws[wave] = v;
    __syncthreads();
    if (threadIdx.x == 0) bsum[blockIdx.x] = ws[0] + ws[1] + ws[2] + ws[3];
}

__global__ __launch_bounds__(128) void scanb_kernel(const int* __restrict__ bsum,
                                                    int* __restrict__ bexcl, int nb) {
    int tid = threadIdx.x;
    int v = (tid < nb) ? bsum[tid] : 0;
    int lane = tid & 63, wave = tid >> 6;
    int s = v;
#pragma unroll
    for (int off = 1; off < 64; off <<= 1) {
        int t = __shfl_up(s, off);
        if (lane >= off) s += t;
    }
    __shared__ int w0sum;
    if (tid == 63) w0sum = s;
    __syncthreads();
    int excl = s - v + (wave ? w0sum : 0);
    if (tid < nb) bexcl[tid] = excl;
}

__global__ __launch_bounds__(256) void expand_kernel(const int* __restrict__ counts,
                                                     const int* __restrict__ bexcl,
                                                     int* __restrict__ offs,
                                                     int* __restrict__ cursor, int n) {
    int i = blockIdx.x * 256 + threadIdx.x;
    int v = (i < n) ? counts[i] : 0;
    int lane = threadIdx.x & 63, wave = threadIdx.x >> 6;
    int s = v;
#pragma unroll
    for (int off = 1; off < 64; off <<= 1) {
        int t = __shfl_up(s, off);
        if (lane >= off) s += t;
    }
    __shared__ int wsum[4];
    if (lane == 63) wsum[wave] = s;
    __syncthreads();
    int add = bexcl[blockIdx.x];
    for (int w = 0; w < wave; ++w) add += wsum[w];
    int excl = add + s - v;
    if (i < n) { offs[i] = excl; cursor[i] = excl; }
    if (i == 0) offs[n] = N_EDGES;
}

__global__ void scatter_kernel(const int* __restrict__ src, const int* __restrict__ dst,
                               int* __restrict__ cursor, int* __restrict__ csr, int n) {
    int e = blockIdx.x * 256 + threadIdx.x;
    if (e < n) {
        int d = dst[e];
        int pos = atomicAdd(&cursor[d], 1);
        csr[pos] = src[e];
    }
}

// ---------------- one-shot weight convert (all layers + input linear) ----------------
// Wt3[l][832][64] bf16: col j -> q(j<256) | permuted k/v (256..767) | s (>=768)
// bias3[l][832] f32. Wlt[64][128] bf16 from linW.

__global__ __launch_bounds__(256) void wcvt_all_kernel(
        const float* __restrict__ Wq, const float* __restrict__ bq,
        const float* __restrict__ Wk, const float* __restrict__ bk,
        const float* __restrict__ Wv, const float* __restrict__ bv,
        const float* __restrict__ Ws, const float* __restrict__ bs,
        const float* __restrict__ linW,
        ushort* __restrict__ Wt3, float* __restrict__ bias3,
        ushort* __restrict__ Wlt) {
    const int PER = 832 * 64;
    int idx = blockIdx.x * 256 + threadIdx.x;
    if (idx < 3 * PER) {
        int l = idx / PER;
        int r = idx - l * PER;
        int j = r >> 6, k = r & 63;
        const float* Wq_l = Wq + (size_t)l * HID * 256;
        const float* Wk_l = Wk + (size_t)l * HID * 256;
        const float* Wv_l = Wv + (size_t)l * HID * 256;
        const float* Ws_l = Ws + (size_t)l * HID * 64;
        float w;
        if (j < 256) {
            w = Wq_l[(size_t)k * 256 + j];
        } else if (j < 768) {
            int pout = j - 256;
            int isv = (pout >> 2) & 1;
            int low2 = pout & 3;
            int g = pout >> 3;
            int srccol = (g >> 4) * 64 + (g & 15) * 4 + low2;
            w = isv ? Wv_l[(size_t)k * 256 + srccol] : Wk_l[(size_t)k * 256 + srccol];
        } else {
            w = Ws_l[(size_t)k * 64 + (j - 768)];
        }
        Wt3[idx] = f2bf(w);
    } else {
        int idx2 = idx - 3 * PER;
        if (idx2 < 64 * DIM_IN) {
            int col = idx2 >> 7, k = idx2 & 127;
            Wlt[idx2] = f2bf(linW[(size_t)k * HID + col]);
        }
    }
    if (idx < 3 * 832) {
        int l = idx / 832, j = idx - l * 832;
        float b;
        if (j < 256) {
            b = bq[l * 256 + j];
        } else if (j < 768) {
            int pout = j - 256;
            int isv = (pout >> 2) & 1;
            int low2 = pout & 3;
            int g = pout >> 3;
            int srccol = (g >> 4) * 64 + (g & 15) * 4 + low2;
            b = isv ? bv[l * 256 + srccol] : bk[l * 256 + srccol];
        } else {
            b = bs[l * 64 + (j - 768)];
        }
        bias3[idx] = b;
    }
}

// ---------------- shared proj phase: 16 h-rows (LDS, f32, stride HOP) @ Wt -> qsb/kvp ----------------
// Operand-swapped MFMA: lane supplies W-col (l&15) as A-row and h-row (l&15) as B-col.
// D: lane holds node-row (l&15), out-cols tile*16 + (l>>4)*4 + [0..4).

__device__ __forceinline__ void proj_rows(const float* __restrict__ ho,
        const ushort* __restrict__ Wt, const float* __restrict__ bias_cat,
        ushort* __restrict__ qsb, ushort* __restrict__ kvp,
        int r0, int lane, int t0, int tstep) {
    int lr = lane & 15;
    int grow = r0 + lr;
    int koff = (lane >> 4) * 8;
    short8 bh[2];
#pragma unroll
    for (int mm = 0; mm < 2; ++mm) {
        const float* hp = ho + lr * HOP + mm * 32 + koff;
        float4 f0 = *(const float4*)hp;
        float4 f1 = *(const float4*)(hp + 4);
        ushort8 u;
        u[0] = f2bf(f0.x); u[1] = f2bf(f0.y); u[2] = f2bf(f0.z); u[3] = f2bf(f0.w);
        u[4] = f2bf(f1.x); u[5] = f2bf(f1.y); u[6] = f2bf(f1.z); u[7] = f2bf(f1.w);
        bh[mm] = __builtin_bit_cast(short8, u);
    }
    bool ok = (grow < N_NODES);
    for (int t = t0; t < 52; t += tstep) {
        const ushort* wb = Wt + (size_t)(t * 16 + lr) * HID + koff;
        short8 w0 = *(const short8*)wb;
        short8 w1 = *(const short8*)(wb + 32);
        f32x4 a_ = (f32x4){0.f, 0.f, 0.f, 0.f};
        a_ = __builtin_amdgcn_mfma_f32_16x16x32_bf16(w0, bh[0], a_, 0, 0, 0);
        a_ = __builtin_amdgcn_mfma_f32_16x16x32_bf16(w1, bh[1], a_, 0, 0, 0);
        int j = t * 16 + ((lane >> 4) << 2);
        float4 bs4 = *(const float4*)(bias_cat + j);
        ushort4v u4;
        u4[0] = f2bf(a_[0] + bs4.x);
        u4[1] = f2bf(a_[1] + bs4.y);
        u4[2] = f2bf(a_[2] + bs4.z);
        u4[3] = f2bf(a_[3] + bs4.w);
        if (ok) {
            ushort* dst;
            if (j < 256)      dst = qsb + (size_t)grow * 320 + j;
            else if (j < 768) dst = kvp + (size_t)grow * 512 + (j - 256);
            else              dst = qsb + (size_t)grow * 320 + 256 + (j - 768);
            *(ushort4v*)dst = u4;
        }
    }
}

// ---------------- fused input linear + layer-0 projection ----------------
// Block: 256 threads, 4 waves, 64 rows. Wave w: rows blk*64 + w*16 (own rows -> no barrier).

__global__ __launch_bounds__(256) void linproj_kernel(const float* __restrict__ x,
        const ushort* __restrict__ Wlt, const float* __restrict__ lb,
        const ushort* __restrict__ Wt0, const float* __restrict__ bias0,
        ushort* __restrict__ qsb, ushort* __restrict__ kvp) {
    __shared__ float ho[64 * HOP];
    int tid = threadIdx.x;
    int w = tid >> 6, l = tid & 63;
    int r0 = blockIdx.x * 64 + w * 16;
    int row = r0 + (l & 15);
    int rowc = (row < N_NODES) ? row : (N_NODES - 1);

    short8 a[4];
#pragma unroll
    for (int kc = 0; kc < 4; ++kc) {
        const float* xp = x + (size_t)rowc * DIM_IN + kc * 32 + (l >> 4) * 8;
        float4 f0 = *(const float4*)xp;
        float4 f1 = *(const float4*)(xp + 4);
        ushort8 u;
        u[0] = f2bf(f0.x); u[1] = f2bf(f0.y); u[2] = f2bf(f0.z); u[3] = f2bf(f0.w);
        u[4] = f2bf(f1.x); u[5] = f2bf(f1.y); u[6] = f2bf(f1.z); u[7] = f2bf(f1.w);
        a[kc] = __builtin_bit_cast(short8, u);
    }

    f32x4 acc[4];
#pragma unroll
    for (int t = 0; t < 4; ++t) acc[t] = (f32x4){0.f, 0.f, 0.f, 0.f};

    const ushort* wb = Wlt + (size_t)(l & 15) * DIM_IN + (l >> 4) * 8;
#pragma unroll
    for (int t = 0; t < 4; ++t) {
#pragma unroll
        for (int kc = 0; kc < 4; ++kc) {
            short8 b = *(const short8*)(wb + (size_t)t * 16 * DIM_IN + kc * 32);
            acc[t] = __builtin_amdgcn_mfma_f32_16x16x32_bf16(b, a[kc], acc[t], 0, 0, 0);
        }
    }

    // h0 (biased, no relu) -> LDS; lane holds row (l&15), cols t*16+(l>>4)*4
    float* hrow = ho + (size_t)(w * 16 + (l & 15)) * HOP;
#pragma unroll
    for (int t = 0; t < 4; ++t) {
        int j = t * 16 + ((l >> 4) << 2);
        float4 bias = *(const float4*)(lb + j);
        float4 o;
        o.x = acc[t][0] + bias.x;
        o.y = acc[t][1] + bias.y;
        o.z = acc[t][2] + bias.z;
        o.w = acc[t][3] + bias.w;
        *(float4*)(hrow + j) = o;
    }
    // wave-local rows: no __syncthreads needed
    proj_rows(ho + (size_t)w * 16 * HOP, Wt0, bias0, qsb, kvp, r0, l, 0, 1);
}

// ---------------- attention for one node (whole wave); result valid on lanes (l>>4)==0 ----------------

__device__ __forceinline__ float4 attn_node(int node, int lane,
        const ushort* __restrict__ qsb, const ushort8* __restrict__ kvp,
        const int* __restrict__ offs, const int* __restrict__ csr) {
    int hh = lane >> 4;
    int cb = (lane & 15) * 4;
    const ushort* nb = qsb + (size_t)node * 320;
    ushort4v qu = *(const ushort4v*)(nb + hh * 64 + cb);
    float qx = bf2f(qu[0]), qy = bf2f(qu[1]), qz = bf2f(qu[2]), qw = bf2f(qu[3]);

    const float SCL = 0.125f * 1.44269504088896340736f;  // 1/sqrt(64) * log2(e)
    float m = -INFINITY, l = 0.f;
    float4 acc = make_float4(0.f, 0.f, 0.f, 0.f);

    int e0 = offs[node], e1 = offs[node + 1];
    int cnt = e1 - e0;

    ushort8 cur = (ushort8)(0);
    ushort8 nxt = (ushort8)(0);
    if (cnt > 0) cur = kvp[(size_t)csr[e0] * 64 + lane];
    if (cnt > 1) nxt = kvp[(size_t)csr[e0 + 1] * 64 + lane];

    for (int i = 0; i < cnt; ++i) {
        ushort8 u = cur;
        cur = nxt;
        if (i + 2 < cnt) nxt = kvp[(size_t)csr[e0 + i + 2] * 64 + lane];

        float p = qx * bf2f(u[0]) + qy * bf2f(u[1]) + qz * bf2f(u[2]) + qw * bf2f(u[3]);
        p += __shfl_xor(p, 1);
        p += __shfl_xor(p, 2);
        p += __shfl_xor(p, 4);
        p += __shfl_xor(p, 8);
        float alpha = p * SCL;
        if (__any(alpha > m)) {
            float nm = fmaxf(m, alpha);
            float sc = exp2f(m - nm);
            l *= sc; acc.x *= sc; acc.y *= sc; acc.z *= sc; acc.w *= sc;
            m = nm;
        }
        float pe = exp2f(alpha - m);
        l += pe;
        acc.x += pe * bf2f(u[4]);
        acc.y += pe * bf2f(u[5]);
        acc.z += pe * bf2f(u[6]);
        acc.w += pe * bf2f(u[7]);
    }

    float inv = (l > 0.f) ? (1.f / l) : 0.f;
    float4 r;
    r.x = acc.x * inv;
    r.y = acc.y * inv;
    r.z = acc.z * inv;
    r.w = acc.w * inv;
    r.x += __shfl_xor(r.x, 16); r.x += __shfl_xor(r.x, 32);
    r.y += __shfl_xor(r.y, 16); r.y += __shfl_xor(r.y, 32);
    r.z += __shfl_xor(r.z, 16); r.z += __shfl_xor(r.z, 32);
    r.w += __shfl_xor(r.w, 16); r.w += __shfl_xor(r.w, 32);

    ushort4v su = *(const ushort4v*)(nb + 256 + cb);
    float4 o;
    o.x = fmaxf(r.x * 0.25f + bf2f(su[0]), 0.f);
    o.y = fmaxf(r.y * 0.25f + bf2f(su[1]), 0.f);
    o.z = fmaxf(r.z * 0.25f + bf2f(su[2]), 0.f);
    o.w = fmaxf(r.w * 0.25f + bf2f(su[3]), 0.f);
    return o;
}

// ---------------- fused edge attention + next-layer projection ----------------
// Block: 512 threads = 8 waves, 16 nodes (wave w owns nodes blk*16 + w*2 + {0,1}).
// Phase 1: attention -> h rows in LDS. Phase 2: cooperative 16-row proj (wave w: tiles w, w+8, ...).

__global__ __launch_bounds__(512) void edgeproj_kernel(const ushort* __restrict__ qsb_in,
        const ushort8* __restrict__ kvp_in,
        const int* __restrict__ offs, const int* __restrict__ csr,
        const ushort* __restrict__ Wt_next, const float* __restrict__ bias_next,
        ushort* __restrict__ qsb_out, ushort* __restrict__ kvp_out) {
    __shared__ float ho[16 * HOP];
    int tid = threadIdx.x;
    int w = tid >> 6, l = tid & 63;
    int nbase = blockIdx.x * 16 + w * 2;
#pragma unroll
    for (int nd = 0; nd < 2; ++nd) {
        int node = nbase + nd;
        float4 o = attn_node(node, l, qsb_in, kvp_in, offs, csr);
        if ((l >> 4) == 0)
            *(float4*)(ho + (size_t)(w * 2 + nd) * HOP + (l & 15) * 4) = o;
    }
    __syncthreads();
    proj_rows(ho, Wt_next, bias_next, qsb_out, kvp_out, blockIdx.x * 16, l, w, 8);
}

// ---------------- plain edge attention (last layer) ----------------

__global__ __launch_bounds__(256) void edge_kernel(const ushort* __restrict__ qsb,
        const ushort8* __restrict__ kvp,
        const int* __restrict__ offs, const int* __restrict__ csr,
        float* __restrict__ hout) {
    int w = threadIdx.x >> 6, l = threadIdx.x & 63;
    int node = blockIdx.x * 4 + w;
    float4 o = attn_node(node, l, qsb, kvp, offs, csr);
    if ((l >> 4) == 0)
        *(float4*)(hout + (size_t)node * HID + (l & 15) * 4) = o;
}

// ---------------- global add pool ----------------

__global__ __launch_bounds__(256) void pool_kernel(const float* __restrict__ h,
                                                   const int* __restrict__ batch,
                                                   float* __restrict__ out) {
    int g = blockIdx.x;
    int lo = 0, hi = N_NODES;
    while (lo < hi) { int mid = (lo + hi) >> 1; if (batch[mid] < g) lo = mid + 1; else hi = mid; }
    int start = lo;
    hi = N_NODES;
    while (lo < hi) { int mid = (lo + hi) >> 1; if (batch[mid] < g + 1) lo = mid + 1; else hi = mid; }
    int end = lo;
    int c = threadIdx.x & 63;
    int sub = threadIdx.x >> 6;
    float acc = 0.f;
    for (int i = start + sub; i < end; i += 4) acc += h[(size_t)i * HID + c];
    __shared__ float lds[4][64];
    lds[sub][c] = acc;
    __syncthreads();
    if (sub == 0) out[g * HID + c] = lds[0][c] + lds[1][c] + lds[2][c] + lds[3][c];
}

// ---------------- launch ----------------

extern "C" void kernel_launch(void* const* d_in, const int* in_sizes, int n_in,
                              void* d_out, int out_size, void* d_ws, size_t ws_size,
                              hipStream_t stream) {
    const float* x    = (const float*)d_in[0];
    const int*   edge = (const int*)d_in[1];
    const int*   batch= (const int*)d_in[2];
    const float* linW = (const float*)d_in[3];
    const float* linb = (const float*)d_in[4];
    const float* Wq   = (const float*)d_in[5];
    const float* bq   = (const float*)d_in[6];
    const float* Wk   = (const float*)d_in[7];
    const float* bk   = (const float*)d_in[8];
    const float* Wv   = (const float*)d_in[9];
    const float* bv   = (const float*)d_in[10];
    const float* Ws   = (const float*)d_in[11];
    const float* bs   = (const float*)d_in[12];
    float* out = (float*)d_out;

    const int* src = edge;
    const int* dst = edge + N_EDGES;

    ushort* qsb0 = (ushort*)d_ws;                         // N*320
    ushort* qsb1 = qsb0 + (size_t)N_NODES * 320;          // N*320
    ushort* kvp0 = qsb1 + (size_t)N_NODES * 320;          // N*512
    ushort* kvp1 = kvp0 + (size_t)N_NODES * 512;          // N*512
    float*  h3   = (float*)kvp1;                          // alias: kvp1 dead when edge2 runs
    int* counts = (int*)(kvp1 + (size_t)N_NODES * 512);
    int* offs   = counts + N_NODES;
    int* cursor = offs + N_NODES + 1;
    int* csr    = cursor + N_NODES;
    int* bsum   = csr + N_EDGES;
    int* bexcl  = bsum + 128;
    ushort* Wt3 = (ushort*)(bexcl + 128);                 // 3*832*64 ushort
    float* bias3 = (float*)(Wt3 + 3 * 832 * 64);          // 3*832 f32
    ushort* Wlt = (ushort*)(bias3 + 3 * 832);             // 64*128 ushort

    const int NB = (N_NODES + 255) / 256;   // 79

    // CSR build (dst fixed across layers)
    hipMemsetAsync(counts, 0, N_NODES * sizeof(int), stream);
    hist_kernel<<<(N_EDGES + 255) / 256, 256, 0, stream>>>(dst, counts, N_EDGES);
    blocksum_kernel<<<NB, 256, 0, stream>>>(counts, bsum, N_NODES);
    scanb_kernel<<<1, 128, 0, stream>>>(bsum, bexcl, NB);
    expand_kernel<<<NB, 256, 0, stream>>>(counts, bexcl, offs, cursor, N_NODES);
    scatter_kernel<<<(N_EDGES + 255) / 256, 256, 0, stream>>>(src, dst, cursor, csr, N_EDGES);

    // one-shot weight conversion
    wcvt_all_kernel<<<(3 * 832 * 64 + 64 * DIM_IN + 255) / 256, 256, 0, stream>>>(
        Wq, bq, Wk, bk, Wv, bv, Ws, bs, linW, Wt3, bias3, Wlt);

    // fused input-linear + layer-0 projection -> qsb0/kvp0
    linproj_kernel<<<(N_NODES + 63) / 64, 256, 0, stream>>>(
        x, Wlt, linb, Wt3, bias3, qsb0, kvp0);

    // layer 0 attention + layer-1 projection
    edgeproj_kernel<<<N_NODES / 16, 512, 0, stream>>>(
        qsb0, (const ushort8*)kvp0, offs, csr,
        Wt3 + (size_t)1 * 832 * 64, bias3 + 832, qsb1, kvp1);

    // layer 1 attention + layer-2 projection
    edgeproj_kernel<<<N_NODES / 16, 512, 0, stream>>>(
        qsb1, (const ushort8*)kvp1, offs, csr,
        Wt3 + (size_t)2 * 832 * 64, bias3 + 1664, qsb0, kvp0);

    // layer 2 attention -> h3
    edge_kernel<<<N_NODES / 4, 256, 0, stream>>>(
        qsb0, (const ushort8*)kvp0, offs, csr, h3);

    pool_kernel<<<GRAPHS, 256, 0, stream>>>(h3, batch, out);
}